// Round 8
// baseline (227.068 us; speedup 1.0000x reference)
//
#include <hip/hip_runtime.h>
#include <math.h>

typedef unsigned short ushort_t;
typedef __attribute__((ext_vector_type(8))) short short8;
typedef __attribute__((ext_vector_type(4))) float f32x4;

#define B_N 4096
#define D_N 512
#define P_N 256
#define C_N 8

// workspace byte offsets
#define ACC_OFF   0                          // [0]=unused, [1]=omega_sumsq, [2]=block counter
#define P2G_OFF   256                        // p2 grouped [256] f32
#define X2_OFF    1280                       // x2 [B][C] f32 (atomically accumulated)
#define XB_OFF    132352                     // x bf16 [B][D]   (memset covers [0, XB_OFF))
#define OMB_OFF   (XB_OFF  + B_N*D_N*2)      // omega bf16 [C][D][D]
#define OMBT_OFF  (OMB_OFF + C_N*D_N*D_N*2)  // omega^T bf16 [C][D][D]
#define GB_OFF    (OMBT_OFF+ C_N*D_N*D_N*2)  // G = om^T om bf16 [C][D][D]
#define UG_OFF    (GB_OFF  + C_N*D_N*D_N*2)  // u grouped bf16 [C][32][D]
#define MINB_OFF  GB_OFF                     // minb [B][C] f32 — aliases Gb (dead after k_u2)

#define MFMA16(a, b, c) __builtin_amdgcn_mfma_f32_16x16x32_bf16(a, b, c, 0, 0, 0)

__device__ inline ushort_t f2bf(float f) {
    union { float f; unsigned u; } v; v.f = f;
    unsigned r = v.u + 0x7FFFu + ((v.u >> 16) & 1u);
    return (ushort_t)(r >> 16);
}

// async global->LDS, 16 B per lane. LDS dst wave-uniform; HW writes base + lane*16.
__device__ __forceinline__ void gll16(const ushort_t* g, ushort_t* l) {
    __builtin_amdgcn_global_load_lds((const __attribute__((address_space(1))) void*)g,
                                     (__attribute__((address_space(3))) void*)l, 16, 0, 0);
}

// ---------- merged cast: blocks [0,1024) cast x; [1024,1536) cast omega (+T, +sumsq) ----------
__global__ void k_cast(const float* __restrict__ x, const float* __restrict__ omega,
                       ushort_t* __restrict__ xb, ushort_t* __restrict__ omb,
                       ushort_t* __restrict__ ombT, float* __restrict__ oss) {
    __shared__ ushort_t T[64][72];
    __shared__ float red[4];
    int t = threadIdx.x;
    if (blockIdx.x < 1024) {
        int idx = blockIdx.x * 256 + t;
        const float4* x4 = (const float4*)x;
        float4 a = x4[idx * 2], b = x4[idx * 2 + 1];
        union { ushort_t s[8]; uint4 v; } o;
        o.s[0] = f2bf(a.x); o.s[1] = f2bf(a.y); o.s[2] = f2bf(a.z); o.s[3] = f2bf(a.w);
        o.s[4] = f2bf(b.x); o.s[5] = f2bf(b.y); o.s[6] = f2bf(b.z); o.s[7] = f2bf(b.w);
        ((uint4*)xb)[idx] = o.v;
        return;
    }
    int bb = blockIdx.x - 1024;
    int c = bb >> 6, r0 = ((bb >> 3) & 7) * 64, c0 = (bb & 7) * 64;
    int r = t >> 2, seg = t & 3;
    const float* src = omega + ((size_t)c * D_N + r0 + r) * D_N + c0 + seg * 16;
    float4 v0 = ((const float4*)src)[0], v1 = ((const float4*)src)[1];
    float4 v2 = ((const float4*)src)[2], v3 = ((const float4*)src)[3];
    float s = v0.x*v0.x + v0.y*v0.y + v0.z*v0.z + v0.w*v0.w
            + v1.x*v1.x + v1.y*v1.y + v1.z*v1.z + v1.w*v1.w
            + v2.x*v2.x + v2.y*v2.y + v2.z*v2.z + v2.w*v2.w
            + v3.x*v3.x + v3.y*v3.y + v3.z*v3.z + v3.w*v3.w;
    union { ushort_t s[16]; uint4 v[2]; } o;
    float vv[16] = {v0.x,v0.y,v0.z,v0.w, v1.x,v1.y,v1.z,v1.w,
                    v2.x,v2.y,v2.z,v2.w, v3.x,v3.y,v3.z,v3.w};
    #pragma unroll
    for (int j = 0; j < 16; ++j) o.s[j] = f2bf(vv[j]);
    uint4* dst = (uint4*)(omb + ((size_t)c * D_N + r0 + r) * D_N + c0 + seg * 16);
    dst[0] = o.v[0]; dst[1] = o.v[1];
    #pragma unroll
    for (int j = 0; j < 16; ++j) T[seg * 16 + j][r] = o.s[j];
    __syncthreads();
    int jr = t >> 2, sg2 = t & 3;
    uint4 w0 = *(uint4*)&T[jr][sg2 * 16];
    uint4 w1 = *(uint4*)&T[jr][sg2 * 16 + 8];
    uint4* dstT = (uint4*)(ombT + ((size_t)c * D_N + c0 + jr) * D_N + r0 + sg2 * 16);
    dstT[0] = w0; dstT[1] = w1;
    #pragma unroll
    for (int off = 32; off > 0; off >>= 1) s += __shfl_down(s, off);
    if ((t & 63) == 0) red[t >> 6] = s;
    __syncthreads();
    if (t == 0) atomicAdd(oss, red[0] + red[1] + red[2] + red[3]);
}

// ---------- G_c = om_c^T om_c : G[c][i][j] = sum_k ombT[c][i][k]*ombT[c][j][k] ----------
// grid (8 i, 8 j, 8 c), 256 thr; 64x64 out tile, wave quadrant 32x32.
__global__ __launch_bounds__(256) void k_G(const ushort_t* __restrict__ ombT,
                                           ushort_t* __restrict__ Gb) {
    int i0 = blockIdx.x * 64, j0 = blockIdx.y * 64, c = blockIdx.z;
    __shared__ ushort_t As[64][72];
    __shared__ ushort_t Bs[64][72];
    int t = threadIdx.x, w = t >> 6, lane = t & 63;
    int qr = w >> 1, qc = w & 1;
    int g = lane >> 4, cl = lane & 15;
    f32x4 acc[2][2];
    #pragma unroll
    for (int mt = 0; mt < 2; ++mt)
        #pragma unroll
        for (int nt = 0; nt < 2; ++nt) acc[mt][nt] = (f32x4){0,0,0,0};
    for (int k0 = 0; k0 < D_N; k0 += 64) {
        __syncthreads();
        {
            int r = t >> 2, sg = t & 3;
            const uint4* ap = (const uint4*)(ombT + ((size_t)c * D_N + i0 + r) * D_N + k0 + sg * 16);
            *(uint4*)&As[r][sg * 16] = ap[0];
            *(uint4*)&As[r][sg * 16 + 8] = ap[1];
            const uint4* bp = (const uint4*)(ombT + ((size_t)c * D_N + j0 + r) * D_N + k0 + sg * 16);
            *(uint4*)&Bs[r][sg * 16] = bp[0];
            *(uint4*)&Bs[r][sg * 16 + 8] = bp[1];
        }
        __syncthreads();
        #pragma unroll
        for (int kk = 0; kk < 2; ++kk) {
            int koff = kk * 32 + g * 8;
            short8 a[2], b[2];
            #pragma unroll
            for (int mt = 0; mt < 2; ++mt)
                a[mt] = *(const short8*)&As[qr * 32 + mt * 16 + cl][koff];
            #pragma unroll
            for (int nt = 0; nt < 2; ++nt)
                b[nt] = *(const short8*)&Bs[qc * 32 + nt * 16 + cl][koff];
            #pragma unroll
            for (int mt = 0; mt < 2; ++mt)
                #pragma unroll
                for (int nt = 0; nt < 2; ++nt)
                    acc[mt][nt] = MFMA16(a[mt], b[nt], acc[mt][nt]);
        }
    }
    #pragma unroll
    for (int mt = 0; mt < 2; ++mt)
        #pragma unroll
        for (int nt = 0; nt < 2; ++nt)
            #pragma unroll
            for (int reg = 0; reg < 4; ++reg) {
                int i = i0 + qr * 32 + mt * 16 + g * 4 + reg;
                int j = j0 + qc * 32 + nt * 16 + cl;
                Gb[((size_t)c * D_N + i) * D_N + j] = f2bf(acc[mt][nt][reg]);
            }
}

// ---------- u[c*32+m][j] = sum_k W[m][k] G_c[k][j] (G symmetric -> row access); p2 = w.u fused ----------
// grid (8 j-slabs, 8 c), 256 thr.
__global__ __launch_bounds__(256) void k_u2(const float* __restrict__ prot,
                                            const ushort_t* __restrict__ Gb,
                                            ushort_t* __restrict__ ug,
                                            float* __restrict__ p2g) {
    int j0 = blockIdx.x * 64, c = blockIdx.y;
    __shared__ ushort_t As[32][72];
    __shared__ ushort_t Bs[64][72];
    int t = threadIdx.x, w = t >> 6, lane = t & 63;
    int g = lane >> 4, cl = lane & 15;
    f32x4 acc[2] = {{0,0,0,0},{0,0,0,0}};
    for (int k0 = 0; k0 < D_N; k0 += 64) {
        __syncthreads();
        {   // stage A: prototypes fp32 -> bf16
            int m = t >> 3, seg = t & 7;
            const float* ap = prot + ((size_t)(c + 8 * m)) * D_N + k0 + seg * 8;
            float4 u0 = ((const float4*)ap)[0], u1 = ((const float4*)ap)[1];
            union { ushort_t s[8]; uint4 v; } o;
            o.s[0]=f2bf(u0.x); o.s[1]=f2bf(u0.y); o.s[2]=f2bf(u0.z); o.s[3]=f2bf(u0.w);
            o.s[4]=f2bf(u1.x); o.s[5]=f2bf(u1.y); o.s[6]=f2bf(u1.z); o.s[7]=f2bf(u1.w);
            *(uint4*)&As[m][seg * 8] = o.v;
        }
        {   // stage B: G rows j0+r (B[n=j][k]=G[j][k] by symmetry)
            int r = t >> 2, sg = t & 3;
            const uint4* bp = (const uint4*)(Gb + ((size_t)c * D_N + j0 + r) * D_N + k0 + sg * 16);
            *(uint4*)&Bs[r][sg * 16] = bp[0];
            *(uint4*)&Bs[r][sg * 16 + 8] = bp[1];
        }
        __syncthreads();
        #pragma unroll
        for (int kk = 0; kk < 2; ++kk) {
            int koff = kk * 32 + g * 8;
            short8 bfr = *(const short8*)&Bs[w * 16 + cl][koff];
            #pragma unroll
            for (int mt = 0; mt < 2; ++mt) {
                short8 afr = *(const short8*)&As[mt * 16 + cl][koff];
                acc[mt] = MFMA16(afr, bfr, acc[mt]);
            }
        }
    }
    #pragma unroll
    for (int mt = 0; mt < 2; ++mt)
        #pragma unroll
        for (int reg = 0; reg < 4; ++reg) {
            float v = acc[mt][reg];
            int m = mt * 16 + g * 4 + reg;
            int j = j0 + w * 16 + cl;
            ug[((size_t)c * 32 + m) * D_N + j] = f2bf(v);
            // p2 partial: w[m][j] * u[m][j], summed over j
            float s = prot[((size_t)(c + 8 * m)) * D_N + j] * v;
            s += __shfl_xor(s, 1); s += __shfl_xor(s, 2);
            s += __shfl_xor(s, 4); s += __shfl_xor(s, 8);
            if (cl == 0) atomicAdd(&p2g[c * 32 + m], s);
        }
}

// ---------- fused x2 + dots-min + (last block) mu/sigmoid/final ----------
// grid (5, 8, 32). blockIdx.x 0..3: x2 i-chunk; ==4: dots slice -> minb.
// BK=32 dbuf global_load_lds pipeline. Swizzle f(r)=(r+(r>>2))&3: LDS pos p of row r
// holds global chunk (p+f(r))&3 -> 16-row b128 column reads are 2-way (free).
__global__ __launch_bounds__(256, 4) void k_x2d(const ushort_t* __restrict__ xb,
                                                const ushort_t* __restrict__ omb,
                                                const ushort_t* __restrict__ ug,
                                                const float* __restrict__ p2g,
                                                float* __restrict__ x2,
                                                float* __restrict__ minb,
                                                const int* __restrict__ y,
                                                float* __restrict__ accs,
                                                float* __restrict__ out) {
    int c  = blockIdx.y;
    int b0 = blockIdx.z * 128;
    int t = threadIdx.x, w = t >> 6, lane = t & 63;
    int g = lane >> 4, cl = lane & 15;
    int srow = lane >> 2, spos = lane & 3;

    __shared__ ushort_t Xs[2][128][32];
    __shared__ ushort_t Os[2][128][32];
    __shared__ float red[128][2];
    __shared__ float red2[4];
    __shared__ int slast;

    if (blockIdx.x < 4) {
        int i0 = blockIdx.x * 128;
        int qr = w >> 1, qc = w & 1;
        f32x4 acc[4][4];
        #pragma unroll
        for (int mt = 0; mt < 4; ++mt)
            #pragma unroll
            for (int nt = 0; nt < 4; ++nt) acc[mt][nt] = (f32x4){0,0,0,0};
        #pragma unroll
        for (int i = 0; i < 2; ++i) {
            int rb = w * 32 + i * 16;
            int r  = rb + srow;
            int cg = (spos + r + (r >> 2)) & 3;
            gll16(xb + (size_t)(b0 + r) * D_N + cg * 8, &Xs[0][rb][0]);
            gll16(omb + ((size_t)c * D_N + i0 + r) * D_N + cg * 8, &Os[0][rb][0]);
        }
        __syncthreads();
        for (int s = 0; s < 16; ++s) {
            int cb = s & 1, nb = cb ^ 1;
            if (s < 15) {
                int k1 = (s + 1) * 32;
                #pragma unroll
                for (int i = 0; i < 2; ++i) {
                    int rb = w * 32 + i * 16;
                    int r  = rb + srow;
                    int cg = (spos + r + (r >> 2)) & 3;
                    gll16(xb + (size_t)(b0 + r) * D_N + k1 + cg * 8, &Xs[nb][rb][0]);
                    gll16(omb + ((size_t)c * D_N + i0 + r) * D_N + k1 + cg * 8, &Os[nb][rb][0]);
                }
            }
            short8 a[4], b[4];
            #pragma unroll
            for (int mt = 0; mt < 4; ++mt) {
                int r = qr * 64 + mt * 16 + cl;
                a[mt] = *(const short8*)&Xs[cb][r][((g - r - (r >> 2)) & 3) * 8];
            }
            #pragma unroll
            for (int nt = 0; nt < 4; ++nt) {
                int r = qc * 64 + nt * 16 + cl;
                b[nt] = *(const short8*)&Os[cb][r][((g - r - (r >> 2)) & 3) * 8];
            }
            #pragma unroll
            for (int mt = 0; mt < 4; ++mt)
                #pragma unroll
                for (int nt = 0; nt < 4; ++nt)
                    acc[mt][nt] = MFMA16(a[mt], b[nt], acc[mt][nt]);
            __syncthreads();
        }
        #pragma unroll
        for (int mt = 0; mt < 4; ++mt)
            #pragma unroll
            for (int reg = 0; reg < 4; ++reg) {
                float s = 0.f;
                #pragma unroll
                for (int nt = 0; nt < 4; ++nt) s += acc[mt][nt][reg] * acc[mt][nt][reg];
                s += __shfl_xor(s, 1); s += __shfl_xor(s, 2);
                s += __shfl_xor(s, 4); s += __shfl_xor(s, 8);
                if (cl == 0) red[qr * 64 + mt * 16 + g * 4 + reg][qc] = s;
            }
        __syncthreads();
        if (t < 128) atomicAdd(&x2[(size_t)(b0 + t) * C_N + c], red[t][0] + red[t][1]);
    } else {
        // dots slice: 128 b x 32 q (class c). Wave w owns b rows [w*32, w*32+32).
        f32x4 acc[2][2];
        #pragma unroll
        for (int mt = 0; mt < 2; ++mt)
            #pragma unroll
            for (int nt = 0; nt < 2; ++nt) acc[mt][nt] = (f32x4){0,0,0,0};
        #pragma unroll
        for (int i = 0; i < 2; ++i) {
            int rb = w * 32 + i * 16;
            int r  = rb + srow;
            int cg = (spos + r + (r >> 2)) & 3;
            gll16(xb + (size_t)(b0 + r) * D_N + cg * 8, &Xs[0][rb][0]);
        }
        if (w < 2) {
            int rb = w * 16;
            int r  = rb + srow;
            int cg = (spos + r + (r >> 2)) & 3;
            gll16(ug + ((size_t)c * 32 + r) * D_N + cg * 8, &Os[0][rb][0]);
        }
        __syncthreads();
        for (int s = 0; s < 16; ++s) {
            int cb = s & 1, nb = cb ^ 1;
            if (s < 15) {
                int k1 = (s + 1) * 32;
                #pragma unroll
                for (int i = 0; i < 2; ++i) {
                    int rb = w * 32 + i * 16;
                    int r  = rb + srow;
                    int cg = (spos + r + (r >> 2)) & 3;
                    gll16(xb + (size_t)(b0 + r) * D_N + k1 + cg * 8, &Xs[nb][rb][0]);
                }
                if (w < 2) {
                    int rb = w * 16;
                    int r  = rb + srow;
                    int cg = (spos + r + (r >> 2)) & 3;
                    gll16(ug + ((size_t)c * 32 + r) * D_N + k1 + cg * 8, &Os[nb][rb][0]);
                }
            }
            short8 a[2], b[2];
            #pragma unroll
            for (int mt = 0; mt < 2; ++mt) {
                int r = w * 32 + mt * 16 + cl;
                a[mt] = *(const short8*)&Xs[cb][r][((g - r - (r >> 2)) & 3) * 8];
            }
            #pragma unroll
            for (int nt = 0; nt < 2; ++nt) {
                int r = nt * 16 + cl;
                b[nt] = *(const short8*)&Os[cb][r][((g - r - (r >> 2)) & 3) * 8];
            }
            #pragma unroll
            for (int mt = 0; mt < 2; ++mt)
                #pragma unroll
                for (int nt = 0; nt < 2; ++nt)
                    acc[mt][nt] = MFMA16(a[mt], b[nt], acc[mt][nt]);
            __syncthreads();
        }
        #pragma unroll
        for (int mt = 0; mt < 2; ++mt)
            #pragma unroll
            for (int reg = 0; reg < 4; ++reg) {
                float v = INFINITY;
                #pragma unroll
                for (int nt = 0; nt < 2; ++nt) {
                    int q = c * 32 + nt * 16 + cl;
                    v = fminf(v, p2g[q] - 2.f * acc[mt][nt][reg]);
                }
                v = fminf(v, __shfl_xor(v, 1)); v = fminf(v, __shfl_xor(v, 2));
                v = fminf(v, __shfl_xor(v, 4)); v = fminf(v, __shfl_xor(v, 8));
                if (cl == 0)
                    minb[(size_t)(b0 + w * 32 + mt * 16 + g * 4 + reg) * C_N + c] = v;
            }
    }

    // ----- last-block fused mu/sigmoid/mean + final -----
    __threadfence();
    if (t == 0)
        slast = (atomicAdd((unsigned*)accs + 2, 1u) == 5u * C_N * (B_N / 128) - 1u);
    __syncthreads();
    if (slast) {
        __threadfence();
        float local = 0.f;
        for (int b = t; b < B_N; b += 256) {
            int yb = y[b];
            float pd[8];
            #pragma unroll
            for (int cc = 0; cc < 8; ++cc)
                pd[cc] = x2[(size_t)b * C_N + cc] + minb[(size_t)b * C_N + cc];
            float pos = pd[yb];
            float neg = INFINITY;
            #pragma unroll
            for (int cc = 0; cc < 8; ++cc)
                if (cc != yb) neg = fminf(neg, pd[cc]);
            float mu = (pos - neg) / (pos + neg);
            local += 1.f / (1.f + expf(-mu));
        }
        #pragma unroll
        for (int off = 32; off > 0; off >>= 1) local += __shfl_down(local, off);
        if ((t & 63) == 0) red2[t >> 6] = local;
        __syncthreads();
        if (t == 0)
            out[0] = (red2[0] + red2[1] + red2[2] + red2[3]) * (1.f / (float)B_N)
                   + 0.01f * sqrtf(accs[1]);
    }
}

extern "C" void kernel_launch(void* const* d_in, const int* in_sizes, int n_in,
                              void* d_out, int out_size, void* d_ws, size_t ws_size,
                              hipStream_t stream) {
    (void)in_sizes; (void)n_in; (void)out_size; (void)ws_size;
    const float* x     = (const float*)d_in[0];
    const int*   y     = (const int*)d_in[1];
    const float* prot  = (const float*)d_in[2];
    const float* omega = (const float*)d_in[3];

    char* ws = (char*)d_ws;
    float*    accs = (float*)(ws + ACC_OFF);
    float*    p2g  = (float*)(ws + P2G_OFF);
    float*    x2   = (float*)(ws + X2_OFF);
    ushort_t* xb   = (ushort_t*)(ws + XB_OFF);
    ushort_t* omb  = (ushort_t*)(ws + OMB_OFF);
    ushort_t* ombT = (ushort_t*)(ws + OMBT_OFF);
    ushort_t* Gb   = (ushort_t*)(ws + GB_OFF);
    ushort_t* ug   = (ushort_t*)(ws + UG_OFF);
    float*    minb = (float*)(ws + MINB_OFF);  // aliases Gb — safe: Gb dead after k_u2

    (void)hipMemsetAsync(ws, 0, XB_OFF, stream);  // accs(+counter), p2g, x2
    k_cast<<<1536, 256, 0, stream>>>(x, omega, xb, omb, ombT, accs + 1);
    k_G   <<<dim3(8, 8, C_N), 256, 0, stream>>>(ombT, Gb);
    k_u2  <<<dim3(8, C_N), 256, 0, stream>>>(prot, Gb, ug, p2g);
    k_x2d <<<dim3(5, C_N, B_N / 128), 256, 0, stream>>>(xb, omb, ug, p2g, x2, minb,
                                                        y, accs, (float*)d_out);
}

// Round 9
// 137.320 us; speedup vs baseline: 1.6536x; 1.6536x over previous
//
#include <hip/hip_runtime.h>
#include <math.h>

typedef unsigned short ushort_t;
typedef __attribute__((ext_vector_type(8))) short short8;
typedef __attribute__((ext_vector_type(4))) float f32x4;

#define B_N 4096
#define D_N 512
#define P_N 256
#define C_N 8

// workspace byte offsets
#define ACC_OFF   0                          // [0]=loss_sum, [1]=omega_sumsq, [2]=counter
#define P2G_OFF   256                        // p2 grouped [256] f32
#define X2_OFF    1280                       // x2 [B][C] f32 (atomically accumulated)
#define XB_OFF    132352                     // x bf16 [B][D]   (memset covers [0, XB_OFF))
#define OMB_OFF   (XB_OFF  + B_N*D_N*2)      // omega bf16 [C][D][D]
#define OMBT_OFF  (OMB_OFF + C_N*D_N*D_N*2)  // omega^T bf16 [C][D][D]
#define GB_OFF    (OMBT_OFF+ C_N*D_N*D_N*2)  // G = om^T om bf16 [C][D][D]
#define UG_OFF    (GB_OFF  + C_N*D_N*D_N*2)  // u grouped bf16 [C][32][D]
#define MINB_OFF  GB_OFF                     // minb [B][C] f32 — aliases Gb (dead after k_u2)

#define MFMA16(a, b, c) __builtin_amdgcn_mfma_f32_16x16x32_bf16(a, b, c, 0, 0, 0)

__device__ inline ushort_t f2bf(float f) {
    union { float f; unsigned u; } v; v.f = f;
    unsigned r = v.u + 0x7FFFu + ((v.u >> 16) & 1u);
    return (ushort_t)(r >> 16);
}

// async global->LDS, 16 B per lane. LDS dst wave-uniform; HW writes base + lane*16.
__device__ __forceinline__ void gll16(const ushort_t* g, ushort_t* l) {
    __builtin_amdgcn_global_load_lds((const __attribute__((address_space(1))) void*)g,
                                     (__attribute__((address_space(3))) void*)l, 16, 0, 0);
}

// ---------- merged cast: blocks [0,1024) cast x; [1024,1536) cast omega (+T, +sumsq) ----------
__global__ void k_cast(const float* __restrict__ x, const float* __restrict__ omega,
                       ushort_t* __restrict__ xb, ushort_t* __restrict__ omb,
                       ushort_t* __restrict__ ombT, float* __restrict__ oss) {
    __shared__ ushort_t T[64][72];
    __shared__ float red[4];
    int t = threadIdx.x;
    if (blockIdx.x < 1024) {
        int idx = blockIdx.x * 256 + t;
        const float4* x4 = (const float4*)x;
        float4 a = x4[idx * 2], b = x4[idx * 2 + 1];
        union { ushort_t s[8]; uint4 v; } o;
        o.s[0] = f2bf(a.x); o.s[1] = f2bf(a.y); o.s[2] = f2bf(a.z); o.s[3] = f2bf(a.w);
        o.s[4] = f2bf(b.x); o.s[5] = f2bf(b.y); o.s[6] = f2bf(b.z); o.s[7] = f2bf(b.w);
        ((uint4*)xb)[idx] = o.v;
        return;
    }
    int bb = blockIdx.x - 1024;
    int c = bb >> 6, r0 = ((bb >> 3) & 7) * 64, c0 = (bb & 7) * 64;
    int r = t >> 2, seg = t & 3;
    const float* src = omega + ((size_t)c * D_N + r0 + r) * D_N + c0 + seg * 16;
    float4 v0 = ((const float4*)src)[0], v1 = ((const float4*)src)[1];
    float4 v2 = ((const float4*)src)[2], v3 = ((const float4*)src)[3];
    float s = v0.x*v0.x + v0.y*v0.y + v0.z*v0.z + v0.w*v0.w
            + v1.x*v1.x + v1.y*v1.y + v1.z*v1.z + v1.w*v1.w
            + v2.x*v2.x + v2.y*v2.y + v2.z*v2.z + v2.w*v2.w
            + v3.x*v3.x + v3.y*v3.y + v3.z*v3.z + v3.w*v3.w;
    union { ushort_t s[16]; uint4 v[2]; } o;
    float vv[16] = {v0.x,v0.y,v0.z,v0.w, v1.x,v1.y,v1.z,v1.w,
                    v2.x,v2.y,v2.z,v2.w, v3.x,v3.y,v3.z,v3.w};
    #pragma unroll
    for (int j = 0; j < 16; ++j) o.s[j] = f2bf(vv[j]);
    uint4* dst = (uint4*)(omb + ((size_t)c * D_N + r0 + r) * D_N + c0 + seg * 16);
    dst[0] = o.v[0]; dst[1] = o.v[1];
    #pragma unroll
    for (int j = 0; j < 16; ++j) T[seg * 16 + j][r] = o.s[j];
    __syncthreads();
    int jr = t >> 2, sg2 = t & 3;
    uint4 w0 = *(uint4*)&T[jr][sg2 * 16];
    uint4 w1 = *(uint4*)&T[jr][sg2 * 16 + 8];
    uint4* dstT = (uint4*)(ombT + ((size_t)c * D_N + c0 + jr) * D_N + r0 + sg2 * 16);
    dstT[0] = w0; dstT[1] = w1;
    #pragma unroll
    for (int off = 32; off > 0; off >>= 1) s += __shfl_down(s, off);
    if ((t & 63) == 0) red[t >> 6] = s;
    __syncthreads();
    if (t == 0) atomicAdd(oss, red[0] + red[1] + red[2] + red[3]);
}

// ---------- G_c = om_c^T om_c ----------
// grid (8 i, 8 j, 8 c), 256 thr; 64x64 out tile, wave quadrant 32x32.
__global__ __launch_bounds__(256) void k_G(const ushort_t* __restrict__ ombT,
                                           ushort_t* __restrict__ Gb) {
    int i0 = blockIdx.x * 64, j0 = blockIdx.y * 64, c = blockIdx.z;
    __shared__ ushort_t As[64][72];
    __shared__ ushort_t Bs[64][72];
    int t = threadIdx.x, w = t >> 6, lane = t & 63;
    int qr = w >> 1, qc = w & 1;
    int g = lane >> 4, cl = lane & 15;
    f32x4 acc[2][2];
    #pragma unroll
    for (int mt = 0; mt < 2; ++mt)
        #pragma unroll
        for (int nt = 0; nt < 2; ++nt) acc[mt][nt] = (f32x4){0,0,0,0};
    for (int k0 = 0; k0 < D_N; k0 += 64) {
        __syncthreads();
        {
            int r = t >> 2, sg = t & 3;
            const uint4* ap = (const uint4*)(ombT + ((size_t)c * D_N + i0 + r) * D_N + k0 + sg * 16);
            *(uint4*)&As[r][sg * 16] = ap[0];
            *(uint4*)&As[r][sg * 16 + 8] = ap[1];
            const uint4* bp = (const uint4*)(ombT + ((size_t)c * D_N + j0 + r) * D_N + k0 + sg * 16);
            *(uint4*)&Bs[r][sg * 16] = bp[0];
            *(uint4*)&Bs[r][sg * 16 + 8] = bp[1];
        }
        __syncthreads();
        #pragma unroll
        for (int kk = 0; kk < 2; ++kk) {
            int koff = kk * 32 + g * 8;
            short8 a[2], b[2];
            #pragma unroll
            for (int mt = 0; mt < 2; ++mt)
                a[mt] = *(const short8*)&As[qr * 32 + mt * 16 + cl][koff];
            #pragma unroll
            for (int nt = 0; nt < 2; ++nt)
                b[nt] = *(const short8*)&Bs[qc * 32 + nt * 16 + cl][koff];
            #pragma unroll
            for (int mt = 0; mt < 2; ++mt)
                #pragma unroll
                for (int nt = 0; nt < 2; ++nt)
                    acc[mt][nt] = MFMA16(a[mt], b[nt], acc[mt][nt]);
        }
    }
    #pragma unroll
    for (int mt = 0; mt < 2; ++mt)
        #pragma unroll
        for (int nt = 0; nt < 2; ++nt)
            #pragma unroll
            for (int reg = 0; reg < 4; ++reg) {
                int i = i0 + qr * 32 + mt * 16 + g * 4 + reg;
                int j = j0 + qc * 32 + nt * 16 + cl;
                Gb[((size_t)c * D_N + i) * D_N + j] = f2bf(acc[mt][nt][reg]);
            }
}

// ---------- u[c*32+m][j] = sum_k W[m][k] G_c[k][j]; p2 = w.u fused ----------
__global__ __launch_bounds__(256) void k_u2(const float* __restrict__ prot,
                                            const ushort_t* __restrict__ Gb,
                                            ushort_t* __restrict__ ug,
                                            float* __restrict__ p2g) {
    int j0 = blockIdx.x * 64, c = blockIdx.y;
    __shared__ ushort_t As[32][72];
    __shared__ ushort_t Bs[64][72];
    int t = threadIdx.x, w = t >> 6, lane = t & 63;
    int g = lane >> 4, cl = lane & 15;
    f32x4 acc[2] = {{0,0,0,0},{0,0,0,0}};
    for (int k0 = 0; k0 < D_N; k0 += 64) {
        __syncthreads();
        {
            int m = t >> 3, seg = t & 7;
            const float* ap = prot + ((size_t)(c + 8 * m)) * D_N + k0 + seg * 8;
            float4 u0 = ((const float4*)ap)[0], u1 = ((const float4*)ap)[1];
            union { ushort_t s[8]; uint4 v; } o;
            o.s[0]=f2bf(u0.x); o.s[1]=f2bf(u0.y); o.s[2]=f2bf(u0.z); o.s[3]=f2bf(u0.w);
            o.s[4]=f2bf(u1.x); o.s[5]=f2bf(u1.y); o.s[6]=f2bf(u1.z); o.s[7]=f2bf(u1.w);
            *(uint4*)&As[m][seg * 8] = o.v;
        }
        {
            int r = t >> 2, sg = t & 3;
            const uint4* bp = (const uint4*)(Gb + ((size_t)c * D_N + j0 + r) * D_N + k0 + sg * 16);
            *(uint4*)&Bs[r][sg * 16] = bp[0];
            *(uint4*)&Bs[r][sg * 16 + 8] = bp[1];
        }
        __syncthreads();
        #pragma unroll
        for (int kk = 0; kk < 2; ++kk) {
            int koff = kk * 32 + g * 8;
            short8 bfr = *(const short8*)&Bs[w * 16 + cl][koff];
            #pragma unroll
            for (int mt = 0; mt < 2; ++mt) {
                short8 afr = *(const short8*)&As[mt * 16 + cl][koff];
                acc[mt] = MFMA16(afr, bfr, acc[mt]);
            }
        }
    }
    #pragma unroll
    for (int mt = 0; mt < 2; ++mt)
        #pragma unroll
        for (int reg = 0; reg < 4; ++reg) {
            float v = acc[mt][reg];
            int m = mt * 16 + g * 4 + reg;
            int j = j0 + w * 16 + cl;
            ug[((size_t)c * 32 + m) * D_N + j] = f2bf(v);
            float s = prot[((size_t)(c + 8 * m)) * D_N + j] * v;
            s += __shfl_xor(s, 1); s += __shfl_xor(s, 2);
            s += __shfl_xor(s, 4); s += __shfl_xor(s, 8);
            if (cl == 0) atomicAdd(&p2g[c * 32 + m], s);
        }
}

// ---------- fused x2 + dots-min: grid (5, 8, 32) — NO grid-wide tail (R8 lesson) ----------
// blockIdx.x 0..3: x2 i-chunk (128x128); ==4: dots slice (128b x 32q) -> minb.
// BK=32 dbuf global_load_lds pipeline, one barrier/iter.
__global__ __launch_bounds__(256, 4) void k_x2d(const ushort_t* __restrict__ xb,
                                                const ushort_t* __restrict__ omb,
                                                const ushort_t* __restrict__ ug,
                                                const float* __restrict__ p2g,
                                                float* __restrict__ x2,
                                                float* __restrict__ minb) {
    int c  = blockIdx.y;
    int b0 = blockIdx.z * 128;
    int t = threadIdx.x, w = t >> 6, lane = t & 63;
    int g = lane >> 4, cl = lane & 15;
    int srow = lane >> 2, spos = lane & 3;

    __shared__ ushort_t Xs[2][128][32];
    __shared__ ushort_t Os[2][128][32];
    __shared__ float red[128][2];

    if (blockIdx.x < 4) {
        int i0 = blockIdx.x * 128;
        int qr = w >> 1, qc = w & 1;
        f32x4 acc[4][4];
        #pragma unroll
        for (int mt = 0; mt < 4; ++mt)
            #pragma unroll
            for (int nt = 0; nt < 4; ++nt) acc[mt][nt] = (f32x4){0,0,0,0};
        #pragma unroll
        for (int i = 0; i < 2; ++i) {
            int rb = w * 32 + i * 16;
            int r  = rb + srow;
            int cg = (spos + r + (r >> 2)) & 3;
            gll16(xb + (size_t)(b0 + r) * D_N + cg * 8, &Xs[0][rb][0]);
            gll16(omb + ((size_t)c * D_N + i0 + r) * D_N + cg * 8, &Os[0][rb][0]);
        }
        __syncthreads();
        for (int s = 0; s < 16; ++s) {
            int cb = s & 1, nb = cb ^ 1;
            if (s < 15) {
                int k1 = (s + 1) * 32;
                #pragma unroll
                for (int i = 0; i < 2; ++i) {
                    int rb = w * 32 + i * 16;
                    int r  = rb + srow;
                    int cg = (spos + r + (r >> 2)) & 3;
                    gll16(xb + (size_t)(b0 + r) * D_N + k1 + cg * 8, &Xs[nb][rb][0]);
                    gll16(omb + ((size_t)c * D_N + i0 + r) * D_N + k1 + cg * 8, &Os[nb][rb][0]);
                }
            }
            short8 a[4], b[4];
            #pragma unroll
            for (int mt = 0; mt < 4; ++mt) {
                int r = qr * 64 + mt * 16 + cl;
                a[mt] = *(const short8*)&Xs[cb][r][((g - r - (r >> 2)) & 3) * 8];
            }
            #pragma unroll
            for (int nt = 0; nt < 4; ++nt) {
                int r = qc * 64 + nt * 16 + cl;
                b[nt] = *(const short8*)&Os[cb][r][((g - r - (r >> 2)) & 3) * 8];
            }
            #pragma unroll
            for (int mt = 0; mt < 4; ++mt)
                #pragma unroll
                for (int nt = 0; nt < 4; ++nt)
                    acc[mt][nt] = MFMA16(a[mt], b[nt], acc[mt][nt]);
            __syncthreads();
        }
        #pragma unroll
        for (int mt = 0; mt < 4; ++mt)
            #pragma unroll
            for (int reg = 0; reg < 4; ++reg) {
                float s = 0.f;
                #pragma unroll
                for (int nt = 0; nt < 4; ++nt) s += acc[mt][nt][reg] * acc[mt][nt][reg];
                s += __shfl_xor(s, 1); s += __shfl_xor(s, 2);
                s += __shfl_xor(s, 4); s += __shfl_xor(s, 8);
                if (cl == 0) red[qr * 64 + mt * 16 + g * 4 + reg][qc] = s;
            }
        __syncthreads();
        if (t < 128) atomicAdd(&x2[(size_t)(b0 + t) * C_N + c], red[t][0] + red[t][1]);
    } else {
        f32x4 acc[2][2];
        #pragma unroll
        for (int mt = 0; mt < 2; ++mt)
            #pragma unroll
            for (int nt = 0; nt < 2; ++nt) acc[mt][nt] = (f32x4){0,0,0,0};
        #pragma unroll
        for (int i = 0; i < 2; ++i) {
            int rb = w * 32 + i * 16;
            int r  = rb + srow;
            int cg = (spos + r + (r >> 2)) & 3;
            gll16(xb + (size_t)(b0 + r) * D_N + cg * 8, &Xs[0][rb][0]);
        }
        if (w < 2) {
            int rb = w * 16;
            int r  = rb + srow;
            int cg = (spos + r + (r >> 2)) & 3;
            gll16(ug + ((size_t)c * 32 + r) * D_N + cg * 8, &Os[0][rb][0]);
        }
        __syncthreads();
        for (int s = 0; s < 16; ++s) {
            int cb = s & 1, nb = cb ^ 1;
            if (s < 15) {
                int k1 = (s + 1) * 32;
                #pragma unroll
                for (int i = 0; i < 2; ++i) {
                    int rb = w * 32 + i * 16;
                    int r  = rb + srow;
                    int cg = (spos + r + (r >> 2)) & 3;
                    gll16(xb + (size_t)(b0 + r) * D_N + k1 + cg * 8, &Xs[nb][rb][0]);
                }
                if (w < 2) {
                    int rb = w * 16;
                    int r  = rb + srow;
                    int cg = (spos + r + (r >> 2)) & 3;
                    gll16(ug + ((size_t)c * 32 + r) * D_N + k1 + cg * 8, &Os[nb][rb][0]);
                }
            }
            short8 a[2], b[2];
            #pragma unroll
            for (int mt = 0; mt < 2; ++mt) {
                int r = w * 32 + mt * 16 + cl;
                a[mt] = *(const short8*)&Xs[cb][r][((g - r - (r >> 2)) & 3) * 8];
            }
            #pragma unroll
            for (int nt = 0; nt < 2; ++nt) {
                int r = nt * 16 + cl;
                b[nt] = *(const short8*)&Os[cb][r][((g - r - (r >> 2)) & 3) * 8];
            }
            #pragma unroll
            for (int mt = 0; mt < 2; ++mt)
                #pragma unroll
                for (int nt = 0; nt < 2; ++nt)
                    acc[mt][nt] = MFMA16(a[mt], b[nt], acc[mt][nt]);
            __syncthreads();
        }
        #pragma unroll
        for (int mt = 0; mt < 2; ++mt)
            #pragma unroll
            for (int reg = 0; reg < 4; ++reg) {
                float v = INFINITY;
                #pragma unroll
                for (int nt = 0; nt < 2; ++nt) {
                    int q = c * 32 + nt * 16 + cl;
                    v = fminf(v, p2g[q] - 2.f * acc[mt][nt][reg]);
                }
                v = fminf(v, __shfl_xor(v, 1)); v = fminf(v, __shfl_xor(v, 2));
                v = fminf(v, __shfl_xor(v, 4)); v = fminf(v, __shfl_xor(v, 8));
                if (cl == 0)
                    minb[(size_t)(b0 + w * 32 + mt * 16 + g * 4 + reg) * C_N + c] = v;
            }
    }
}

// ---------- per-row mu -> sigmoid -> sum; last of 16 blocks writes final ----------
__global__ void k_mu(const float* __restrict__ x2, const float* __restrict__ minb,
                     const int* __restrict__ y, float* __restrict__ accs,
                     float* __restrict__ out) {
    int t = threadIdx.x;
    int b = blockIdx.x * 256 + t;
    int yb = y[b];
    float d[8];
    #pragma unroll
    for (int cc = 0; cc < 8; ++cc)
        d[cc] = x2[(size_t)b * C_N + cc] + minb[(size_t)b * C_N + cc];
    float pos = d[yb];
    float neg = INFINITY;
    #pragma unroll
    for (int cc = 0; cc < 8; ++cc)
        if (cc != yb) neg = fminf(neg, d[cc]);
    float mu = (pos - neg) / (pos + neg);
    float s = 1.f / (1.f + expf(-mu));
    #pragma unroll
    for (int off = 32; off > 0; off >>= 1) s += __shfl_down(s, off);
    __shared__ float red[4];
    __shared__ int lastf;
    if ((t & 63) == 0) red[t >> 6] = s;
    __syncthreads();
    if (t == 0) {
        atomicAdd(&accs[0], red[0] + red[1] + red[2] + red[3]);
        __threadfence();
        unsigned n = atomicAdd((unsigned*)accs + 2, 1u);
        lastf = (n == (unsigned)(B_N / 256 - 1));
    }
    __syncthreads();
    if (lastf && t == 0) {
        __threadfence();
        out[0] = accs[0] * (1.f / (float)B_N) + 0.01f * sqrtf(accs[1]);
    }
}

extern "C" void kernel_launch(void* const* d_in, const int* in_sizes, int n_in,
                              void* d_out, int out_size, void* d_ws, size_t ws_size,
                              hipStream_t stream) {
    (void)in_sizes; (void)n_in; (void)out_size; (void)ws_size;
    const float* x     = (const float*)d_in[0];
    const int*   y     = (const int*)d_in[1];
    const float* prot  = (const float*)d_in[2];
    const float* omega = (const float*)d_in[3];

    char* ws = (char*)d_ws;
    float*    accs = (float*)(ws + ACC_OFF);
    float*    p2g  = (float*)(ws + P2G_OFF);
    float*    x2   = (float*)(ws + X2_OFF);
    ushort_t* xb   = (ushort_t*)(ws + XB_OFF);
    ushort_t* omb  = (ushort_t*)(ws + OMB_OFF);
    ushort_t* ombT = (ushort_t*)(ws + OMBT_OFF);
    ushort_t* Gb   = (ushort_t*)(ws + GB_OFF);
    ushort_t* ug   = (ushort_t*)(ws + UG_OFF);
    float*    minb = (float*)(ws + MINB_OFF);  // aliases Gb — safe: Gb dead after k_u2

    (void)hipMemsetAsync(ws, 0, XB_OFF, stream);  // accs(+counter), p2g, x2
    k_cast<<<1536, 256, 0, stream>>>(x, omega, xb, omb, ombT, accs + 1);
    k_G   <<<dim3(8, 8, C_N), 256, 0, stream>>>(ombT, Gb);
    k_u2  <<<dim3(8, C_N), 256, 0, stream>>>(prot, Gb, ug, p2g);
    k_x2d <<<dim3(5, C_N, B_N / 128), 256, 0, stream>>>(xb, omb, ug, p2g, x2, minb);
    k_mu  <<<B_N / 256, 256, 0, stream>>>(x2, minb, y, accs, (float*)d_out);
}